// Round 1
// baseline (2148.637 us; speedup 1.0000x reference)
//
#include <hip/hip_runtime.h>

typedef unsigned short u16;
typedef unsigned int u32;
typedef __bf16 bf16x8 __attribute__((ext_vector_type(8)));
typedef float f32x4 __attribute__((ext_vector_type(4)));

__device__ __forceinline__ u16 f2bf(float f) {
  union { float f; u32 u; } c; c.f = f;
  return (u16)((c.u + 0x7fffu + ((c.u >> 16) & 1u)) >> 16);
}
__device__ __forceinline__ float bf2f(u16 h) {
  union { u32 u; float f; } c; c.u = ((u32)h) << 16;
  return c.f;
}
__device__ __forceinline__ float bflo(u32 u) {
  union { u32 u; float f; } c; c.u = u << 16; return c.f;
}
__device__ __forceinline__ float bfhi(u32 u) {
  union { u32 u; float f; } c; c.u = u & 0xffff0000u; return c.f;
}

// Convert a weight slice W[n, col0 + k] (f32, row stride src_stride) into
// bf16 [N][Kd] zero-padded along K.
__global__ __launch_bounds__(256) void cvt_w(const float* __restrict__ src,
                                             u16* __restrict__ dst, int N,
                                             int Ks, int Kd, int src_stride,
                                             int col0) {
  int i = blockIdx.x * 256 + threadIdx.x;
  if (i >= N * Kd) return;
  int n = i / Kd, k = i % Kd;
  float v = (k < Ks) ? src[(size_t)n * src_stride + col0 + k] : 0.f;
  dst[i] = f2bf(v);
}

// C[M,256] = A[M,Kpad] * W[256,Kpad]^T  with epilogue variants.
// ASRC: 0 = A from f32 global [M][lda] (guarded, converted)
//       1 = A from bf16 global [M][Kpad]
//       2 = A row r = bf16( Ab[idx1[r]] - Ab2[idx2[r]] )   (both [*,Kpad])
// EPI:  0 = write bf16 acc -> outb0, bf16 relu(acc) -> outb1
//       1 = v=acc+bias[c]; bf16 v -> outb0; relu(v) f32 -> outf
//       2 = v=acc+bf2f(addb[idx]); bf16 relu(v) -> outb1
//       3 = v=acc+bf2f(addb[idx]); relu(v) f32 -> outf
template <int ASRC, int EPI>
__global__ __launch_bounds__(256) void gemm_bt(
    const float* __restrict__ Af, int lda, int Kreal,
    const u16* __restrict__ Ab, const u16* __restrict__ Ab2,
    const int* __restrict__ idx1, const int* __restrict__ idx2,
    const u16* __restrict__ Bw, int M, int Kpad,
    const u16* __restrict__ addb, const float* __restrict__ bias,
    u16* __restrict__ outb0, u16* __restrict__ outb1,
    float* __restrict__ outf) {
  __shared__ u16 As[128][72];  // +8 pad: row stride 144B, 2-way banks (free)
  __shared__ u16 Bs[128][72];

  const int tid = threadIdx.x;
  const int lane = tid & 63, wid = tid >> 6;
  const int wm = (wid >> 1) * 64, wn = (wid & 1) * 64;
  const int m0 = blockIdx.x * 128, n0 = blockIdx.y * 128;

  f32x4 acc[4][4];
#pragma unroll
  for (int i = 0; i < 4; ++i)
#pragma unroll
    for (int j = 0; j < 4; ++j) acc[i][j] = (f32x4)(0.f);

  const int ar = lane & 15, ak = (lane >> 4) * 8;

  for (int ks = 0; ks < Kpad; ks += 64) {
    __syncthreads();
#pragma unroll
    for (int p = 0; p < 4; ++p) {
      int chunk = p * 256 + tid;
      int row = chunk >> 3;
      int col = (chunk & 7) * 8;
      int gr = m0 + row;
      uint4 v = make_uint4(0u, 0u, 0u, 0u);
      if (ASRC == 0) {
        u16 tmp[8];
#pragma unroll
        for (int i = 0; i < 8; ++i) {
          int k = ks + col + i;
          float x = (gr < M && k < Kreal) ? Af[(size_t)gr * lda + k] : 0.f;
          tmp[i] = f2bf(x);
        }
        v.x = (u32)tmp[0] | ((u32)tmp[1] << 16);
        v.y = (u32)tmp[2] | ((u32)tmp[3] << 16);
        v.z = (u32)tmp[4] | ((u32)tmp[5] << 16);
        v.w = (u32)tmp[6] | ((u32)tmp[7] << 16);
      } else if (ASRC == 1) {
        if (gr < M)
          v = *reinterpret_cast<const uint4*>(Ab + (size_t)gr * Kpad + ks + col);
      } else {
        if (gr < M) {
          int r1 = idx1[gr];
          int r2 = idx2[gr];
          uint4 va = *reinterpret_cast<const uint4*>(Ab + (size_t)r1 * Kpad + ks + col);
          uint4 vb = *reinterpret_cast<const uint4*>(Ab2 + (size_t)r2 * Kpad + ks + col);
          u16 tmp[8];
          tmp[0] = f2bf(bflo(va.x) - bflo(vb.x));
          tmp[1] = f2bf(bfhi(va.x) - bfhi(vb.x));
          tmp[2] = f2bf(bflo(va.y) - bflo(vb.y));
          tmp[3] = f2bf(bfhi(va.y) - bfhi(vb.y));
          tmp[4] = f2bf(bflo(va.z) - bflo(vb.z));
          tmp[5] = f2bf(bfhi(va.z) - bfhi(vb.z));
          tmp[6] = f2bf(bflo(va.w) - bflo(vb.w));
          tmp[7] = f2bf(bfhi(va.w) - bfhi(vb.w));
          v.x = (u32)tmp[0] | ((u32)tmp[1] << 16);
          v.y = (u32)tmp[2] | ((u32)tmp[3] << 16);
          v.z = (u32)tmp[4] | ((u32)tmp[5] << 16);
          v.w = (u32)tmp[6] | ((u32)tmp[7] << 16);
        }
      }
      *reinterpret_cast<uint4*>(&As[row][col]) = v;
      // B tile: W rows n0+row, always in bounds (N=256)
      uint4 bv = *reinterpret_cast<const uint4*>(Bw + (size_t)(n0 + row) * Kpad + ks + col);
      *reinterpret_cast<uint4*>(&Bs[row][col]) = bv;
    }
    __syncthreads();
#pragma unroll
    for (int kk = 0; kk < 64; kk += 32) {
      bf16x8 a[4], b[4];
#pragma unroll
      for (int t = 0; t < 4; ++t)
        a[t] = *reinterpret_cast<const bf16x8*>(&As[wm + t * 16 + ar][kk + ak]);
#pragma unroll
      for (int t = 0; t < 4; ++t)
        b[t] = *reinterpret_cast<const bf16x8*>(&Bs[wn + t * 16 + ar][kk + ak]);
#pragma unroll
      for (int i = 0; i < 4; ++i)
#pragma unroll
        for (int j = 0; j < 4; ++j)
          acc[i][j] = __builtin_amdgcn_mfma_f32_16x16x32_bf16(a[i], b[j], acc[i][j], 0, 0, 0);
    }
  }

  const int er = (lane >> 4) * 4;
  const int ec = lane & 15;
#pragma unroll
  for (int i = 0; i < 4; ++i) {
#pragma unroll
    for (int j = 0; j < 4; ++j) {
      int rbase = m0 + wm + i * 16 + er;
      int c = n0 + wn + j * 16 + ec;
#pragma unroll
      for (int q = 0; q < 4; ++q) {
        int r = rbase + q;
        if (r >= M) continue;
        size_t idx = (size_t)r * 256 + c;
        float v = acc[i][j][q];
        if (EPI == 0) {
          outb0[idx] = f2bf(v);
          outb1[idx] = f2bf(v > 0.f ? v : 0.f);
        } else if (EPI == 1) {
          v += bias[c];
          outb0[idx] = f2bf(v);
          outf[idx] = v > 0.f ? v : 0.f;
        } else if (EPI == 2) {
          v += bf2f(addb[idx]);
          outb1[idx] = f2bf(v > 0.f ? v : 0.f);
        } else {
          v += bf2f(addb[idx]);
          outf[idx] = v > 0.f ? v : 0.f;
        }
      }
    }
  }
}

// a_msg[a][:] = sum_j msg[a2b[a][j]][:]  (bf16 in/out, f32 accum)
__global__ __launch_bounds__(256) void gather_sum(const u16* __restrict__ msg,
                                                  const int* __restrict__ a2b,
                                                  u16* __restrict__ amsg,
                                                  int n_atoms) {
  int wave = threadIdx.x >> 6, lane = threadIdx.x & 63;
  int atom = blockIdx.x * 4 + wave;
  if (atom >= n_atoms) return;
  float s0 = 0.f, s1 = 0.f, s2 = 0.f, s3 = 0.f;
  int base = atom * 6;
#pragma unroll
  for (int j = 0; j < 6; ++j) {
    int b = a2b[base + j];
    ushort4 v = *reinterpret_cast<const ushort4*>(msg + (size_t)b * 256 + lane * 4);
    s0 += bf2f(v.x);
    s1 += bf2f(v.y);
    s2 += bf2f(v.z);
    s3 += bf2f(v.w);
  }
  ushort4 o = make_ushort4(f2bf(s0), f2bf(s1), f2bf(s2), f2bf(s3));
  *reinterpret_cast<ushort4*>(amsg + (size_t)atom * 256 + lane * 4) = o;
}

__global__ __launch_bounds__(256) void mol_mean(const float* __restrict__ dfin,
                                                float* __restrict__ out) {
  int mol = blockIdx.x, c = threadIdx.x;
  const float* p = dfin + (size_t)mol * (42 * 256) + c;
  float s = 0.f;
#pragma unroll
  for (int a = 0; a < 42; ++a) s += p[a * 256];
  out[(size_t)mol * 256 + c] = s * (1.0f / 42.0f);
}

extern "C" void kernel_launch(void* const* d_in, const int* in_sizes, int n_in,
                              void* d_out, int out_size, void* d_ws,
                              size_t ws_size, hipStream_t stream) {
  const float* f_atoms = (const float*)d_in[0];
  const float* f_bonds = (const float*)d_in[1];
  const float* W_i = (const float*)d_in[2];
  const float* W_h = (const float*)d_in[3];
  const float* W_o = (const float*)d_in[4];
  const float* b_o = (const float*)d_in[5];
  const int* a2b = (const int*)d_in[6];
  const int* b2a = (const int*)d_in[7];
  const int* b2revb = (const int*)d_in[8];

  const int NA = 168000, NB = 360000, H = 256;
  const size_t SZ_BH = (size_t)NB * H * 2;  // 184,320,000 B
  const size_t SZ_AH = (size_t)NA * H * 2;  //  86,016,000 B

  char* ws = (char*)d_ws;
  u16* inp_b = (u16*)ws;  ws += SZ_BH;
  u16* msgA  = (u16*)ws;  ws += SZ_BH;
  u16* msgB  = (u16*)ws;  ws += SZ_BH;
  u16* amsg  = (u16*)ws;  ws += SZ_AH;
  u16* base_b = (u16*)ws; ws += SZ_AH;
  u16* Wi_b  = (u16*)ws;  ws += 256 * 192 * 2;
  u16* Wh_b  = (u16*)ws;  ws += 256 * 256 * 2;
  u16* Wo1_b = (u16*)ws;  ws += 256 * 192 * 2;
  u16* Wo2_b = (u16*)ws;  ws += 256 * 256 * 2;

  float* out = (float*)d_out;
  float* d0 = out;
  float* d1 = d0 + (size_t)NA * H;
  float* d2 = d1 + (size_t)NA * H;
  float* dfin = d2 + (size_t)NA * H;
  float* mol = dfin + (size_t)NA * H;

  dim3 blk(256);
  cvt_w<<<dim3((256 * 192 + 255) / 256), blk, 0, stream>>>(W_i, Wi_b, 256, 147, 192, 147, 0);
  cvt_w<<<dim3((256 * 256 + 255) / 256), blk, 0, stream>>>(W_h, Wh_b, 256, 256, 256, 256, 0);
  cvt_w<<<dim3((256 * 192 + 255) / 256), blk, 0, stream>>>(W_o, Wo1_b, 256, 133, 192, 389, 0);
  cvt_w<<<dim3((256 * 256 + 255) / 256), blk, 0, stream>>>(W_o, Wo2_b, 256, 256, 256, 389, 133);

  dim3 gB((NB + 127) / 128, 2);
  dim3 gA((NA + 127) / 128, 2);

  // inp = f_bonds @ W_i^T ; msgA = relu(inp)
  gemm_bt<0, 0><<<gB, blk, 0, stream>>>(f_bonds, 147, 147, nullptr, nullptr,
                                        nullptr, nullptr, Wi_b, NB, 192,
                                        nullptr, nullptr, inp_b, msgA, nullptr);
  // base = f_atoms @ W_o1^T + b_o ; d0 = relu(base)
  gemm_bt<0, 1><<<gA, blk, 0, stream>>>(f_atoms, 133, 133, nullptr, nullptr,
                                        nullptr, nullptr, Wo1_b, NA, 192,
                                        nullptr, b_o, base_b, nullptr, d0);

  u16* mcur = msgA;
  u16* mnext = msgB;
  float* douts[3] = {d1, d2, dfin};
  for (int d = 0; d < 3; ++d) {
    gather_sum<<<dim3(NA / 4), blk, 0, stream>>>(mcur, a2b, amsg, NA);
    // d_{d+1} = relu(base + amsg @ W_o2^T)
    gemm_bt<1, 3><<<gA, blk, 0, stream>>>(nullptr, 0, 0, amsg, nullptr, nullptr,
                                          nullptr, Wo2_b, NA, 256, base_b,
                                          nullptr, nullptr, nullptr, douts[d]);
    if (d < 2) {
      // msg' = relu(inp + (amsg[b2a] - msg[b2revb]) @ W_h^T)
      gemm_bt<2, 2><<<gB, blk, 0, stream>>>(nullptr, 0, 0, amsg, mcur, b2a,
                                            b2revb, Wh_b, NB, 256, inp_b,
                                            nullptr, nullptr, mnext, nullptr);
      u16* t = mcur; mcur = mnext; mnext = t;
    }
  }
  mol_mean<<<dim3(4000), blk, 0, stream>>>(dfin, mol);
}

// Round 2
// 1754.694 us; speedup vs baseline: 1.2245x; 1.2245x over previous
//
#include <hip/hip_runtime.h>

typedef unsigned short u16;
typedef unsigned int u32;
typedef __bf16 bf16x8 __attribute__((ext_vector_type(8)));
typedef float f32x4 __attribute__((ext_vector_type(4)));

__device__ __forceinline__ u16 f2bf(float f) {
  union { float f; u32 u; } c; c.f = f;
  return (u16)((c.u + 0x7fffu + ((c.u >> 16) & 1u)) >> 16);
}
__device__ __forceinline__ float bf2f(u16 h) {
  union { u32 u; float f; } c; c.u = ((u32)h) << 16;
  return c.f;
}
__device__ __forceinline__ float bflo(u32 u) {
  union { u32 u; float f; } c; c.u = u << 16; return c.f;
}
__device__ __forceinline__ float bfhi(u32 u) {
  union { u32 u; float f; } c; c.u = u & 0xffff0000u; return c.f;
}

// Convert a weight slice W[n, col0 + k] (f32, row stride src_stride) into
// bf16 [N][Kd] zero-padded along K.
__global__ __launch_bounds__(256) void cvt_w(const float* __restrict__ src,
                                             u16* __restrict__ dst, int N,
                                             int Ks, int Kd, int src_stride,
                                             int col0) {
  int i = blockIdx.x * 256 + threadIdx.x;
  if (i >= N * Kd) return;
  int n = i / Kd, k = i % Kd;
  float v = (k < Ks) ? src[(size_t)n * src_stride + col0 + k] : 0.f;
  dst[i] = f2bf(v);
}

// C[M,256] = A[M,KPAD] * W[256,KPAD]^T.
// BM=64, BN=256 (full), 4 waves of 64x64. A staged to LDS once (one barrier),
// B read directly from global (weights are L2-resident, broadcast).
// ASRC: 0 = A from f32 global [M][lda] (k<Kreal guard, converted)
//       1 = A from bf16 global [M][KPAD]
//       2 = A row r = bf16( Ab[idx1[r]] - Ab2[idx2[r]] )   (both [*,KPAD])
// EPI:  0 = write bf16 acc -> outb0, bf16 relu(acc) -> outb1
//       1 = v=acc+bias[c]; bf16 v -> outb0; relu(v) f32 -> outf
//       2 = v=acc+bf2f(addb[idx]); bf16 relu(v) -> outb1
//       3 = v=acc+bf2f(addb[idx]); relu(v) f32 -> outf
// M must be a multiple of 64 (360000 / 168000 both are).
template <int ASRC, int EPI, int KPAD>
__global__ __launch_bounds__(256, 3) void gemm2(
    const float* __restrict__ Af, int lda, int Kreal,
    const u16* __restrict__ Ab, const u16* __restrict__ Ab2,
    const int* __restrict__ idx1, const int* __restrict__ idx2,
    const u16* __restrict__ Bw,
    const u16* __restrict__ addb, const float* __restrict__ bias,
    u16* __restrict__ outb0, u16* __restrict__ outb1,
    float* __restrict__ outf) {
  constexpr int LDK = KPAD + 8;  // 16B-slot stride odd -> rows spread banks
  __shared__ u16 As[64 * LDK];

  const int tid = threadIdx.x;
  const int lane = tid & 63, wid = tid >> 6;
  const int wn = wid * 64;           // this wave's N offset (0..192)
  const int m0 = blockIdx.x * 64;

  // ---- stage A[64][KPAD] into LDS, once ----
  if (ASRC == 2) {
    const int r = tid >> 2, part = tid & 3;   // 4 threads per row
    const int gr = m0 + r;
    const int r1 = idx1[gr], r2 = idx2[gr];
    const u16* pa = Ab + (size_t)r1 * KPAD + part * (KPAD / 4);
    const u16* pb = Ab2 + (size_t)r2 * KPAD + part * (KPAD / 4);
    u16* dst = &As[r * LDK + part * (KPAD / 4)];
#pragma unroll
    for (int i = 0; i < KPAD / 32; ++i) {  // (KPAD/4)/8 uint4 per thread
      uint4 va = *reinterpret_cast<const uint4*>(pa + i * 8);
      uint4 vb = *reinterpret_cast<const uint4*>(pb + i * 8);
      uint4 v;
      u16 t0, t1;
      t0 = f2bf(bflo(va.x) - bflo(vb.x));
      t1 = f2bf(bfhi(va.x) - bfhi(vb.x));
      v.x = (u32)t0 | ((u32)t1 << 16);
      t0 = f2bf(bflo(va.y) - bflo(vb.y));
      t1 = f2bf(bfhi(va.y) - bfhi(vb.y));
      v.y = (u32)t0 | ((u32)t1 << 16);
      t0 = f2bf(bflo(va.z) - bflo(vb.z));
      t1 = f2bf(bfhi(va.z) - bfhi(vb.z));
      v.z = (u32)t0 | ((u32)t1 << 16);
      t0 = f2bf(bflo(va.w) - bflo(vb.w));
      t1 = f2bf(bfhi(va.w) - bfhi(vb.w));
      v.w = (u32)t0 | ((u32)t1 << 16);
      *reinterpret_cast<uint4*>(dst + i * 8) = v;
    }
  } else if (ASRC == 1) {
    constexpr int NCH = 64 * KPAD / 8;  // uint4 chunks in tile
#pragma unroll
    for (int p = 0; p < NCH / 256; ++p) {
      int ch = p * 256 + tid;
      int row = ch / (KPAD / 8);
      int c8 = ch % (KPAD / 8);
      uint4 v = *reinterpret_cast<const uint4*>(Ab + (size_t)m0 * KPAD + (size_t)ch * 8);
      *reinterpret_cast<uint4*>(&As[row * LDK + c8 * 8]) = v;
    }
  } else {
    constexpr int NE = 64 * KPAD;
#pragma unroll
    for (int p = 0; p < NE / 256; ++p) {
      int e = p * 256 + tid;
      int row = e / KPAD, k = e % KPAD;
      float x = (k < Kreal) ? Af[(size_t)(m0 + row) * lda + k] : 0.f;
      As[row * LDK + k] = f2bf(x);
    }
  }
  __syncthreads();

  f32x4 acc[4][4];
#pragma unroll
  for (int i = 0; i < 4; ++i)
#pragma unroll
    for (int j = 0; j < 4; ++j) acc[i][j] = (f32x4)(0.f);

  const int ar = lane & 15, ak = (lane >> 4) * 8;

#pragma unroll
  for (int kk = 0; kk < KPAD; kk += 32) {
    bf16x8 a[4], b[4];
#pragma unroll
    for (int t = 0; t < 4; ++t)
      a[t] = *reinterpret_cast<const bf16x8*>(&As[(t * 16 + ar) * LDK + kk + ak]);
#pragma unroll
    for (int t = 0; t < 4; ++t)
      b[t] = *reinterpret_cast<const bf16x8*>(Bw + (size_t)(wn + t * 16 + ar) * KPAD + kk + ak);
#pragma unroll
    for (int i = 0; i < 4; ++i)
#pragma unroll
      for (int j = 0; j < 4; ++j)
        acc[i][j] = __builtin_amdgcn_mfma_f32_16x16x32_bf16(a[i], b[j], acc[i][j], 0, 0, 0);
  }

  const int er = (lane >> 4) * 4;
  const int ec = lane & 15;
#pragma unroll
  for (int i = 0; i < 4; ++i) {
#pragma unroll
    for (int j = 0; j < 4; ++j) {
      int rbase = m0 + i * 16 + er;
      int c = wn + j * 16 + ec;
#pragma unroll
      for (int q = 0; q < 4; ++q) {
        int r = rbase + q;
        size_t idx = (size_t)r * 256 + c;
        float v = acc[i][j][q];
        if (EPI == 0) {
          outb0[idx] = f2bf(v);
          outb1[idx] = f2bf(v > 0.f ? v : 0.f);
        } else if (EPI == 1) {
          v += bias[c];
          outb0[idx] = f2bf(v);
          outf[idx] = v > 0.f ? v : 0.f;
        } else if (EPI == 2) {
          v += bf2f(addb[idx]);
          outb1[idx] = f2bf(v > 0.f ? v : 0.f);
        } else {
          v += bf2f(addb[idx]);
          outf[idx] = v > 0.f ? v : 0.f;
        }
      }
    }
  }
}

// a_msg[a][:] = sum_j msg[a2b[a][j]][:]  (bf16 in/out, f32 accum)
__global__ __launch_bounds__(256) void gather_sum(const u16* __restrict__ msg,
                                                  const int* __restrict__ a2b,
                                                  u16* __restrict__ amsg,
                                                  int n_atoms) {
  int wave = threadIdx.x >> 6, lane = threadIdx.x & 63;
  int atom = blockIdx.x * 4 + wave;
  if (atom >= n_atoms) return;
  float s0 = 0.f, s1 = 0.f, s2 = 0.f, s3 = 0.f;
  int base = atom * 6;
#pragma unroll
  for (int j = 0; j < 6; ++j) {
    int b = a2b[base + j];
    ushort4 v = *reinterpret_cast<const ushort4*>(msg + (size_t)b * 256 + lane * 4);
    s0 += bf2f(v.x);
    s1 += bf2f(v.y);
    s2 += bf2f(v.z);
    s3 += bf2f(v.w);
  }
  ushort4 o = make_ushort4(f2bf(s0), f2bf(s1), f2bf(s2), f2bf(s3));
  *reinterpret_cast<ushort4*>(amsg + (size_t)atom * 256 + lane * 4) = o;
}

__global__ __launch_bounds__(256) void mol_mean(const float* __restrict__ dfin,
                                                float* __restrict__ out) {
  int mol = blockIdx.x, c = threadIdx.x;
  const float* p = dfin + (size_t)mol * (42 * 256) + c;
  float s = 0.f;
#pragma unroll
  for (int a = 0; a < 42; ++a) s += p[a * 256];
  out[(size_t)mol * 256 + c] = s * (1.0f / 42.0f);
}

extern "C" void kernel_launch(void* const* d_in, const int* in_sizes, int n_in,
                              void* d_out, int out_size, void* d_ws,
                              size_t ws_size, hipStream_t stream) {
  const float* f_atoms = (const float*)d_in[0];
  const float* f_bonds = (const float*)d_in[1];
  const float* W_i = (const float*)d_in[2];
  const float* W_h = (const float*)d_in[3];
  const float* W_o = (const float*)d_in[4];
  const float* b_o = (const float*)d_in[5];
  const int* a2b = (const int*)d_in[6];
  const int* b2a = (const int*)d_in[7];
  const int* b2revb = (const int*)d_in[8];

  const int NA = 168000, NB = 360000, H = 256;
  const size_t SZ_BH = (size_t)NB * H * 2;
  const size_t SZ_AH = (size_t)NA * H * 2;

  char* ws = (char*)d_ws;
  u16* inp_b = (u16*)ws;  ws += SZ_BH;
  u16* msgA  = (u16*)ws;  ws += SZ_BH;
  u16* msgB  = (u16*)ws;  ws += SZ_BH;
  u16* amsg  = (u16*)ws;  ws += SZ_AH;
  u16* base_b = (u16*)ws; ws += SZ_AH;
  u16* Wi_b  = (u16*)ws;  ws += 256 * 192 * 2;
  u16* Wh_b  = (u16*)ws;  ws += 256 * 256 * 2;
  u16* Wo1_b = (u16*)ws;  ws += 256 * 192 * 2;
  u16* Wo2_b = (u16*)ws;  ws += 256 * 256 * 2;

  float* out = (float*)d_out;
  float* d0 = out;
  float* d1 = d0 + (size_t)NA * H;
  float* d2 = d1 + (size_t)NA * H;
  float* dfin = d2 + (size_t)NA * H;
  float* mol = dfin + (size_t)NA * H;

  dim3 blk(256);
  cvt_w<<<dim3((256 * 192 + 255) / 256), blk, 0, stream>>>(W_i, Wi_b, 256, 147, 192, 147, 0);
  cvt_w<<<dim3((256 * 256 + 255) / 256), blk, 0, stream>>>(W_h, Wh_b, 256, 256, 256, 256, 0);
  cvt_w<<<dim3((256 * 192 + 255) / 256), blk, 0, stream>>>(W_o, Wo1_b, 256, 133, 192, 389, 0);
  cvt_w<<<dim3((256 * 256 + 255) / 256), blk, 0, stream>>>(W_o, Wo2_b, 256, 256, 256, 389, 133);

  dim3 gB(NB / 64);  // 5625
  dim3 gA(NA / 64);  // 2625

  // inp = f_bonds @ W_i^T ; msgA = relu(inp)
  gemm2<0, 0, 192><<<gB, blk, 0, stream>>>(f_bonds, 147, 147, nullptr, nullptr,
                                           nullptr, nullptr, Wi_b, nullptr,
                                           nullptr, inp_b, msgA, nullptr);
  // base = f_atoms @ W_o1^T + b_o ; d0 = relu(base)
  gemm2<0, 1, 192><<<gA, blk, 0, stream>>>(f_atoms, 133, 133, nullptr, nullptr,
                                           nullptr, nullptr, Wo1_b, nullptr,
                                           b_o, base_b, nullptr, d0);

  u16* mcur = msgA;
  u16* mnext = msgB;
  float* douts[3] = {d1, d2, dfin};
  for (int d = 0; d < 3; ++d) {
    gather_sum<<<dim3(NA / 4), blk, 0, stream>>>(mcur, a2b, amsg, NA);
    // d_{d+1} = relu(base + amsg @ W_o2^T)
    gemm2<1, 3, 256><<<gA, blk, 0, stream>>>(nullptr, 0, 0, amsg, nullptr,
                                             nullptr, nullptr, Wo2_b, base_b,
                                             nullptr, nullptr, nullptr, douts[d]);
    if (d < 2) {
      // msg' = relu(inp + (amsg[b2a] - msg[b2revb]) @ W_h^T)
      gemm2<2, 2, 256><<<gB, blk, 0, stream>>>(nullptr, 0, 0, amsg, mcur, b2a,
                                               b2revb, Wh_b, inp_b, nullptr,
                                               nullptr, mnext, nullptr);
      u16* t = mcur; mcur = mnext; mnext = t;
    }
  }
  mol_mean<<<dim3(4000), blk, 0, stream>>>(dfin, mol);
}